// Round 17
// baseline (193.004 us; speedup 1.0000x reference)
//
#include <hip/hip_runtime.h>

#define N_NODES 100000
#define N_EDGES 3200000
#define D 16

#define TILE 128                           // dst nodes per bucket
#define NB ((N_NODES + TILE - 1) / TILE)   // 782 buckets
#define CAP 4608                           // per-bucket ebuf region (mean 4096, +8 sigma)
#define NBLK 500                           // scatter blocks
#define SEG (N_EDGES / NBLK)               // 6400 edges per scatter block
#define BINT 1024                          // threads for pre kernel
#define CVTB 391                           // cvt blocks: ceil(400000/1024)
#define LT 512                             // threads for layer kernels (= TILE*4)
#define N4 (N_NODES * D / 4)               // 400000 float4 quarters

// Clang vector types (HIP_vector_type is rejected by nontemporal builtins)
typedef unsigned u32x4 __attribute__((ext_vector_type(4)));
typedef float    f32x4 __attribute__((ext_vector_type(4)));

// ---- bf16 helpers (RNE) ----
__device__ __forceinline__ unsigned packbf(float a, float b) {
    unsigned ua = __float_as_uint(a); ua += 0x7FFFu + ((ua >> 16) & 1u);
    unsigned ub = __float_as_uint(b); ub += 0x7FFFu + ((ub >> 16) & 1u);
    return (ua >> 16) | (ub & 0xFFFF0000u);
}
#define BLO(u) __uint_as_float((u) << 16)
#define BHI(u) __uint_as_float((u) & 0xFFFF0000u)

// ---- fused pre-pass: blocks [0,NBLK) bucket-scatter edges; rest convert x->bf16 ----
// packed entry: (dst & 127) << 17 | src   (src < 2^17)
__global__ __launch_bounds__(BINT, 8) void pre_kernel(
        const float* __restrict__ x, unsigned* __restrict__ xbf,
        const int* __restrict__ src, const int* __restrict__ dst,
        int* __restrict__ cursor, unsigned* __restrict__ ebuf) {
    __shared__ int lcnt[NB];
    __shared__ int ldiff[NB];
    __shared__ unsigned sorted[SEG];
    __shared__ unsigned short sbkt[SEG];
    __shared__ int wsum[16];
    int tid = threadIdx.x;

    if (blockIdx.x >= NBLK) {              // ---- cvt path ----
        int t = (blockIdx.x - NBLK) * BINT + tid;
        if (t < N4) {
            float4 v = *(const float4*)(x + (size_t)t * 4);
            uint2 o; o.x = packbf(v.x, v.y); o.y = packbf(v.z, v.w);
            *(uint2*)(xbf + (size_t)t * 2) = o;
        }
        return;
    }

    // ---- scatter path ----
    for (int i = tid; i < NB; i += BINT) lcnt[i] = 0;
    __syncthreads();
    int b0 = blockIdx.x * SEG;
    for (int e = b0 + tid * 4; e < b0 + SEG; e += BINT * 4) {
        int4 d4 = *(const int4*)(dst + e);
        atomicAdd(&lcnt[d4.x >> 7], 1);
        atomicAdd(&lcnt[d4.y >> 7], 1);
        atomicAdd(&lcnt[d4.z >> 7], 1);
        atomicAdd(&lcnt[d4.w >> 7], 1);
    }
    __syncthreads();
    // wave-shfl scan over NB counters (1/thread), reserve global space
    {
        int lane = tid & 63, wv = tid >> 6;
        int v = (tid < NB) ? lcnt[tid] : 0;
        int s = v;
        #pragma unroll
        for (int d_ = 1; d_ < 64; d_ <<= 1) {
            int u = __shfl_up(s, d_, 64);
            if (lane >= d_) s += u;
        }
        if (lane == 63) wsum[wv] = s;
        __syncthreads();
        if (tid == 0) {
            int a = 0;
            #pragma unroll
            for (int i = 0; i < 16; i++) { int t_ = wsum[i]; wsum[i] = a; a += t_; }
        }
        __syncthreads();
        int excl = wsum[wv] + s - v;
        if (tid < NB) {
            int g = v ? (tid * CAP + atomicAdd(&cursor[tid], v)) : 0;
            ldiff[tid] = g - excl;
            lcnt[tid] = excl;              // running local cursor
        }
        __syncthreads();
    }
    // re-read edges (L2-warm), place into bucket-sorted LDS
    for (int e = b0 + tid * 4; e < b0 + SEG; e += BINT * 4) {
        int4 d4 = *(const int4*)(dst + e);
        int4 s4 = *(const int4*)(src + e);
        int b_, pos;
        b_ = d4.x >> 7; pos = atomicAdd(&lcnt[b_], 1);
        sorted[pos] = ((unsigned)(d4.x & 127) << 17) | (unsigned)s4.x; sbkt[pos] = (unsigned short)b_;
        b_ = d4.y >> 7; pos = atomicAdd(&lcnt[b_], 1);
        sorted[pos] = ((unsigned)(d4.y & 127) << 17) | (unsigned)s4.y; sbkt[pos] = (unsigned short)b_;
        b_ = d4.z >> 7; pos = atomicAdd(&lcnt[b_], 1);
        sorted[pos] = ((unsigned)(d4.z & 127) << 17) | (unsigned)s4.z; sbkt[pos] = (unsigned short)b_;
        b_ = d4.w >> 7; pos = atomicAdd(&lcnt[b_], 1);
        sorted[pos] = ((unsigned)(d4.w & 127) << 17) | (unsigned)s4.w; sbkt[pos] = (unsigned short)b_;
    }
    __syncthreads();
    // coalesced write-out
    for (int i = tid; i < SEG; i += BINT) {
        int b_ = sbkt[i];
        ebuf[ldiff[b_] + i] = sorted[i];
    }
}

// ---- shared aggregation + transform body ----
// 4-lane group per node; 2 lanes/edge, 16B bf16 gathers, software-pipelined.
// self_f32 nullable (layer 0 reads fp32 x; later layers read the bf16 mirror).
// emit_bf: write bf16 mirror (intermediate) else fp32 out (final, nt store).
#define LDG(j) (*(const uint4*)(xbf + (size_t)(se2[(j) + lane2] & 0x1FFFF) * 8 + ho))
#define ACC8(g) do { \
    acc[0] += BLO((g).x); acc[1] += BHI((g).x); acc[2] += BLO((g).y); acc[3] += BHI((g).y); \
    acc[4] += BLO((g).z); acc[5] += BHI((g).z); acc[6] += BLO((g).w); acc[7] += BHI((g).w); } while (0)

__device__ __forceinline__ void agg_xform(
    const float* __restrict__ self_f32, const unsigned* __restrict__ xbf,
    const unsigned* se2, const int* lofs, int n_loc,
    const float* sWl, const float* sWc, const float* sbc,
    float* __restrict__ xout, unsigned* __restrict__ xbf_out,
    int emit_bf, int b, int N, int tid) {
    int q = tid & 3;
    int n = b * TILE + n_loc;
    if (n >= N) return;

    // self row issued early to overlap the gather loop
    float xv[4];
    if (self_f32) {
        float4 xq = *(const float4*)(self_f32 + (size_t)n * D + q * 4);
        xv[0] = xq.x; xv[1] = xq.y; xv[2] = xq.z; xv[3] = xq.w;
    } else {
        uint2 gx = *(const uint2*)(xbf + (size_t)n * 8 + q * 2);
        xv[0] = BLO(gx.x); xv[1] = BHI(gx.x); xv[2] = BLO(gx.y); xv[3] = BHI(gx.y);
    }

    int s0 = lofs[n_loc];
    int s1 = lofs[n_loc + 1];
    int deg = s1 - s0;
    int lane2 = q >> 1;          // edge parity this lane covers
    int ho = (q & 1) * 4;        // uint offset of row half (16B)

    float acc[8] = {0.f,0.f,0.f,0.f,0.f,0.f,0.f,0.f};
    int end8 = s0 + (deg & ~7);
    int i = s0;
    if (i < end8) {
        uint4 c0 = LDG(i + 0), c1 = LDG(i + 2), c2 = LDG(i + 4), c3 = LDG(i + 6);
        i += 8;
        for (; i < end8; i += 8) {
            uint4 n0 = LDG(i + 0), n1 = LDG(i + 2), n2 = LDG(i + 4), n3 = LDG(i + 6);
            ACC8(c0); ACC8(c1); ACC8(c2); ACC8(c3);
            c0 = n0; c1 = n1; c2 = n2; c3 = n3;
        }
        ACC8(c0); ACC8(c1); ACC8(c2); ACC8(c3);
    }
    for (; i + 2 <= s1; i += 2) {
        uint4 g = LDG(i);
        ACC8(g);
    }
    if (i < s1 && lane2 == 0) {              // odd leftover edge: lanes q=0,1 only
        uint4 g = *(const uint4*)(xbf + (size_t)(se2[i] & 0x1FFFF) * 8 + ho);
        ACC8(g);
    }
    #pragma unroll
    for (int k = 0; k < 8; k++) acc[k] += __shfl_xor(acc[k], 2, 4);  // combine parities

    // redistribute half-row sums -> quarter layout: lane q wants f[4q+k]
    int srcAbs = (tid & 63 & ~3) | (q >> 1);
    float inv = 1.0f / fmaxf((float)deg, 1.0f);
    float a[4];
    #pragma unroll
    for (int k = 0; k < 4; k++) {
        float lo = __shfl(acc[k], srcAbs);
        float hi = __shfl(acc[4 + k], srcAbs);
        a[k] = ((q & 1) ? hi : lo) * inv;
    }

    float o[4];
    #pragma unroll
    for (int j = 0; j < D; j++) {
        float p = 0.f;
        #pragma unroll
        for (int k = 0; k < 4; k++) {
            int kk = q * 4 + k;
            p += a[k] * sWl[j * D + kk] + xv[k] * sWc[j * D + kk];
        }
        p += __shfl_xor(p, 1, 4);
        p += __shfl_xor(p, 2, 4);
        if ((j >> 2) == q) o[j & 3] = p + sbc[j];
    }
    if (emit_bf) {
        uint2 ob; ob.x = packbf(o[0], o[1]); ob.y = packbf(o[2], o[3]);
        *(uint2*)(xbf_out + (size_t)n * 8 + q * 2) = ob;
    } else {
        f32x4 ov = { o[0], o[1], o[2], o[3] };
        __builtin_nontemporal_store(ov, (f32x4*)(xout + (size_t)n * D + q * 4));
    }
}

// ---- layer 1: LDS counting sort + degree rank + agg/transform ----
__global__ void layer0_kernel(
        const float* __restrict__ xin, const unsigned* __restrict__ xbf,
        unsigned* __restrict__ ebuf, const int* __restrict__ cnt,
        int* __restrict__ node_start, int* __restrict__ gperm,
        const float* __restrict__ Wl, const float* __restrict__ bl,
        const float* __restrict__ Wr, const float* __restrict__ Wlin,
        const float* __restrict__ blin,
        unsigned* __restrict__ xbf_out, int N) {
    __shared__ unsigned se[CAP];
    __shared__ unsigned se2[CAP];
    __shared__ int lcnt[TILE];
    __shared__ int lofs[TILE + 1];
    __shared__ int sdeg[TILE];
    __shared__ int perm[TILE];
    __shared__ float sWl[D * D];
    __shared__ float sWc[D * D];
    __shared__ float sbc[D];

    int tid = threadIdx.x;
    int b = blockIdx.x;
    int base = b * CAP;
    int nE = min(cnt[b], CAP);
    int nE4 = (nE + 3) >> 2;

    if (tid < D * D) { sWl[tid] = Wl[tid]; sWc[tid] = Wr[tid] + Wlin[tid]; }
    if (tid < D) sbc[tid] = bl[tid] + blin[tid];
    if (tid < TILE) lcnt[tid] = 0;
    // uint4 nt staging of bucket edges (single-use stream)
    for (int i = tid; i < nE4; i += LT)
        ((u32x4*)se)[i] = __builtin_nontemporal_load(&((const u32x4*)(ebuf + base))[i]);
    __syncthreads();
    for (int i = tid; i < nE; i += LT)
        atomicAdd(&lcnt[se[i] >> 17], 1);
    __syncthreads();
    // single-wave shfl scan over TILE counters (2/lane)
    if (tid < 64) {
        int l2 = tid * 2;
        int c0 = lcnt[l2], c1 = lcnt[l2 + 1];
        int v = c0 + c1, s = v;
        #pragma unroll
        for (int d_ = 1; d_ < 64; d_ <<= 1) {
            int u = __shfl_up(s, d_, 64);
            if (tid >= d_) s += u;
        }
        int excl = s - v;
        lofs[l2] = excl; sdeg[l2] = c0; lcnt[l2] = excl;
        node_start[b * TILE + l2] = excl;
        int e1 = excl + c0;
        lofs[l2 + 1] = e1; sdeg[l2 + 1] = c1; lcnt[l2 + 1] = e1;
        node_start[b * TILE + l2 + 1] = e1;
        if (tid == 63) lofs[TILE] = s;       // == nE
    }
    __syncthreads();
    // degree rank (desc)
    if (tid < TILE) {
        int dm = sdeg[tid];
        int r = 0;
        for (int j = 0; j < TILE; j++) {
            int dj = sdeg[j];
            r += (dj > dm) || (dj == dm && j < tid);
        }
        perm[r] = tid;
        gperm[b * TILE + r] = tid;
    }
    // reorder into sorted se2
    for (int i = tid; i < nE; i += LT) {
        unsigned p = se[i];
        int pos = atomicAdd(&lcnt[p >> 17], 1);
        se2[pos] = p;
    }
    __syncthreads();
    for (int i = tid; i < nE4; i += LT)      // uint4 nt sorted write-back
        __builtin_nontemporal_store(((const u32x4*)se2)[i], &((u32x4*)(ebuf + base))[i]);

    agg_xform(xin, xbf, se2, lofs, perm[tid >> 2], sWl, sWc, sbc,
              nullptr, xbf_out, 1, b, N, tid);
}

// ---- layers 2/3: stage sorted edges, agg/transform ----
__global__ __launch_bounds__(LT, 8) void layerN_kernel(
        const unsigned* __restrict__ xbf,
        const unsigned* __restrict__ ebuf, const int* __restrict__ cnt,
        const int* __restrict__ node_start, const int* __restrict__ gperm,
        const float* __restrict__ Wl, const float* __restrict__ bl,
        const float* __restrict__ Wr, const float* __restrict__ Wlin,
        const float* __restrict__ blin,
        float* __restrict__ xout, unsigned* __restrict__ xbf_out,
        int emit_bf, int N) {
    __shared__ unsigned se2[CAP];
    __shared__ int lofs[TILE + 1];
    __shared__ float sWl[D * D];
    __shared__ float sWc[D * D];
    __shared__ float sbc[D];

    int tid = threadIdx.x;
    int b = blockIdx.x;
    int base = b * CAP;
    int nE = min(cnt[b], CAP);
    int nE4 = (nE + 3) >> 2;

    if (tid < D * D) { sWl[tid] = Wl[tid]; sWc[tid] = Wr[tid] + Wlin[tid]; }
    if (tid < D) sbc[tid] = bl[tid] + blin[tid];
    if (tid < TILE) lofs[tid] = node_start[b * TILE + tid];
    if (tid == 0) lofs[TILE] = nE;
    for (int i = tid; i < nE4; i += LT)      // uint4 nt staging (single-use stream)
        ((u32x4*)se2)[i] = __builtin_nontemporal_load(&((const u32x4*)(ebuf + base))[i]);
    int n_loc = gperm[b * TILE + (tid >> 2)];
    __syncthreads();

    agg_xform(nullptr, xbf, se2, lofs, n_loc, sWl, sWc, sbc,
              xout, xbf_out, emit_bf, b, N, tid);
}

extern "C" void kernel_launch(void* const* d_in, const int* in_sizes, int n_in,
                              void* d_out, int out_size, void* d_ws, size_t ws_size,
                              hipStream_t stream) {
    const float* x    = (const float*)d_in[0];
    const int*   ei   = (const int*)d_in[1];   // (2, E): first E = src, next E = dst
    const float* Wl   = (const float*)d_in[2];
    const float* bl   = (const float*)d_in[3];
    const float* Wr   = (const float*)d_in[4];
    const float* Wlin = (const float*)d_in[5];
    const float* blin = (const float*)d_in[6];
    float* out = (float*)d_out;

    const int* src = ei;
    const int* dst = ei + N_EDGES;

    char* w = (char*)d_ws;
    unsigned* ebuf   = (unsigned*)w;  w += (size_t)NB * CAP * 4;        // 14.4 MB
    unsigned* xbf0   = (unsigned*)w;  w += (size_t)N_NODES * 8 * 4;     // 3.2 MB
    unsigned* xbf1   = (unsigned*)w;  w += (size_t)N_NODES * 8 * 4;     // 3.2 MB
    int*   cursor    = (int*)w;       w += (size_t)NB * 4;
    int*   node_start= (int*)w;       w += (size_t)NB * TILE * 4;       // 400 KB
    int*   gperm     = (int*)w;       w += (size_t)NB * TILE * 4;       // 400 KB

    hipMemsetAsync(cursor, 0, (size_t)NB * 4, stream);
    pre_kernel<<<NBLK + CVTB, BINT, 0, stream>>>(x, xbf0, src, dst, cursor, ebuf);

    // layer 0: self = fp32 x, gathers xbf0, emits xbf1
    layer0_kernel<<<NB, LT, 0, stream>>>(
        x, xbf0, ebuf, cursor, node_start, gperm,
        Wl, bl, Wr, Wlin, blin, xbf1, N_NODES);
    // layer 1: self+gathers xbf1, emits xbf0 (overwrite ok: layer0 done)
    layerN_kernel<<<NB, LT, 0, stream>>>(
        xbf1, ebuf, cursor, node_start, gperm,
        Wl + D * D, bl + D, Wr + D * D, Wlin + D * D, blin + D,
        nullptr, xbf0, 1, N_NODES);
    // layer 2: self+gathers xbf0, emits fp32 out (nt store)
    layerN_kernel<<<NB, LT, 0, stream>>>(
        xbf0, ebuf, cursor, node_start, gperm,
        Wl + 2 * D * D, bl + 2 * D, Wr + 2 * D * D, Wlin + 2 * D * D, blin + 2 * D,
        out, nullptr, 0, N_NODES);
}